// Round 4
// baseline (130.760 us; speedup 1.0000x reference)
//
#include <hip/hip_runtime.h>
#include <hip/hip_bf16.h>

// out[i,j] = sum_k relu(a@feats^T)[i,k] * ((b@feats^T)[j,k] <= 0)
// Na=Nb=1024, D=512, K=256.
//
// SINGLE kernel launch (launch gaps ~10us each dominated the 3-kernel chain):
//   phase 0: f32 -> bf16 split planes. a->(h,m); b,feats->(h,m,l).
//   [grid barrier]
//   phase 1: stage1 MFMA. Block bx does its A-job (p tile, 3 MFMA/iter) and B-job
//            (msk tile, 6 MFMA/iter) interleaved in ONE k-loop sharing feats frags
//            -> 2 independent acc chains, latency hidden. Mask sign uses 3-term
//            split (error ~2^-24 rel -> f32-equivalent sign; absmax stays 8.0).
//   [grid barrier]
//   phase 2: out(1024x1024) = p @ msk^T, 64x64 tile/block, MFMA bf16.
// Grid barriers: manual release/acquire with device-scope atomics; 256 blocks of
// 4 waves are trivially co-resident (capacity 2048 waves/CU-pool) -> deadlock-free.
// Barrier cells zeroed by a captured hipMemsetAsync (ws is re-poisoned 0xAA).

typedef short bf16x8 __attribute__((ext_vector_type(8)));
typedef float f32x4  __attribute__((ext_vector_type(4)));

__device__ inline void split3(float x, __hip_bfloat16& h, __hip_bfloat16& m, __hip_bfloat16& l) {
    h = __float2bfloat16(x);
    float r1 = x - __bfloat162float(h);
    m = __float2bfloat16(r1);
    float r2 = r1 - __bfloat162float(m);
    l = __float2bfloat16(r2);
}

__device__ inline void grid_barrier(unsigned* cnt, unsigned* flag, int nblk) {
    __syncthreads();
    if (threadIdx.x == 0) {
        __threadfence();                       // release: publish this block's writes
        if (atomicAdd(cnt, 1u) == (unsigned)(nblk - 1)) {
            atomicExch(flag, 1u);              // last arrival opens the gate
        } else {
            while (atomicAdd(flag, 0u) == 0u) { __builtin_amdgcn_s_sleep(1); }
        }
        __threadfence();                       // acquire: see other blocks' writes
    }
    __syncthreads();
}

__global__ __launch_bounds__(256) void fused_kernel(
    const float* __restrict__ a, const float* __restrict__ b, const float* __restrict__ f,
    unsigned* __restrict__ bar,
    __hip_bfloat16* __restrict__ Ah, __hip_bfloat16* __restrict__ Am,
    __hip_bfloat16* __restrict__ Bh, __hip_bfloat16* __restrict__ Bm, __hip_bfloat16* __restrict__ Bl,
    __hip_bfloat16* __restrict__ Fh, __hip_bfloat16* __restrict__ Fm, __hip_bfloat16* __restrict__ Fl,
    __hip_bfloat16* __restrict__ pbf, __hip_bfloat16* __restrict__ mbf,
    float* __restrict__ out)
{
    const int tid = threadIdx.x;
    const int t   = blockIdx.x * 256 + tid;     // 0..65535

    // ---------------- phase 0: convert ----------------
    // a: 131072 float4 -> 2/thread (h,m planes)
    #pragma unroll
    for (int r = 0; r < 2; r++) {
        int i4 = (t + r * 65536) * 4;
        float4 v = *(const float4*)(a + i4);
        __hip_bfloat16 h[4] __attribute__((aligned(8)));
        __hip_bfloat16 m[4] __attribute__((aligned(8)));
        __hip_bfloat16 l;
        split3(v.x, h[0], m[0], l); split3(v.y, h[1], m[1], l);
        split3(v.z, h[2], m[2], l); split3(v.w, h[3], m[3], l);
        *(short4*)((short*)Ah + i4) = *(const short4*)h;
        *(short4*)((short*)Am + i4) = *(const short4*)m;
    }
    // b: 131072 float4 -> 2/thread (h,m,l planes)
    #pragma unroll
    for (int r = 0; r < 2; r++) {
        int i4 = (t + r * 65536) * 4;
        float4 v = *(const float4*)(b + i4);
        __hip_bfloat16 h[4] __attribute__((aligned(8)));
        __hip_bfloat16 m[4] __attribute__((aligned(8)));
        __hip_bfloat16 l[4] __attribute__((aligned(8)));
        split3(v.x, h[0], m[0], l[0]); split3(v.y, h[1], m[1], l[1]);
        split3(v.z, h[2], m[2], l[2]); split3(v.w, h[3], m[3], l[3]);
        *(short4*)((short*)Bh + i4) = *(const short4*)h;
        *(short4*)((short*)Bm + i4) = *(const short4*)m;
        *(short4*)((short*)Bl + i4) = *(const short4*)l;
    }
    // feats: 32768 float4 -> threads t<32768 do 1 (h,m,l planes)
    if (t < 32768) {
        int i4 = t * 4;
        float4 v = *(const float4*)(f + i4);
        __hip_bfloat16 h[4] __attribute__((aligned(8)));
        __hip_bfloat16 m[4] __attribute__((aligned(8)));
        __hip_bfloat16 l[4] __attribute__((aligned(8)));
        split3(v.x, h[0], m[0], l[0]); split3(v.y, h[1], m[1], l[1]);
        split3(v.z, h[2], m[2], l[2]); split3(v.w, h[3], m[3], l[3]);
        *(short4*)((short*)Fh + i4) = *(const short4*)h;
        *(short4*)((short*)Fm + i4) = *(const short4*)m;
        *(short4*)((short*)Fl + i4) = *(const short4*)l;
    }

    grid_barrier(bar + 0, bar + 1, gridDim.x);

    // ---------------- phase 1: stage1 (A-job + B-job interleaved) ----------------
    {
        const int jb = blockIdx.x;            // job id 0..255
        const int m0 = (jb >> 3) * 32;        // 32 row-tiles
        const int n0 = (jb & 7) * 32;         // 8 feats-tiles
        const int w  = tid >> 6;
        const int lane = tid & 63;
        const int wi = w >> 1, wj = w & 1;
        const int l15 = lane & 15;
        const int q   = lane >> 4;

        const int ra = (m0 + wi * 16 + l15) * 512;
        const int rf = (n0 + wj * 16 + l15) * 512;
        const short* ah_p = (const short*)Ah + ra;
        const short* am_p = (const short*)Am + ra;
        const short* bh_p = (const short*)Bh + ra;
        const short* bm_p = (const short*)Bm + ra;
        const short* bl_p = (const short*)Bl + ra;
        const short* fh_p = (const short*)Fh + rf;
        const short* fm_p = (const short*)Fm + rf;
        const short* fl_p = (const short*)Fl + rf;

        f32x4 accA = {0.f, 0.f, 0.f, 0.f};
        f32x4 accB = {0.f, 0.f, 0.f, 0.f};

        #pragma unroll 4
        for (int k0 = 0; k0 < 512; k0 += 32) {
            const int ko = k0 + q * 8;
            bf16x8 ah = *(const bf16x8*)(ah_p + ko);
            bf16x8 am = *(const bf16x8*)(am_p + ko);
            bf16x8 bh = *(const bf16x8*)(bh_p + ko);
            bf16x8 bm = *(const bf16x8*)(bm_p + ko);
            bf16x8 bl = *(const bf16x8*)(bl_p + ko);
            bf16x8 fh = *(const bf16x8*)(fh_p + ko);
            bf16x8 fm = *(const bf16x8*)(fm_p + ko);
            bf16x8 fl = *(const bf16x8*)(fl_p + ko);
            accA = __builtin_amdgcn_mfma_f32_16x16x32_bf16(ah, fh, accA, 0, 0, 0);
            accB = __builtin_amdgcn_mfma_f32_16x16x32_bf16(bh, fh, accB, 0, 0, 0);
            accA = __builtin_amdgcn_mfma_f32_16x16x32_bf16(ah, fm, accA, 0, 0, 0);
            accB = __builtin_amdgcn_mfma_f32_16x16x32_bf16(bh, fm, accB, 0, 0, 0);
            accA = __builtin_amdgcn_mfma_f32_16x16x32_bf16(am, fh, accA, 0, 0, 0);
            accB = __builtin_amdgcn_mfma_f32_16x16x32_bf16(bm, fh, accB, 0, 0, 0);
            accB = __builtin_amdgcn_mfma_f32_16x16x32_bf16(bh, fl, accB, 0, 0, 0);
            accB = __builtin_amdgcn_mfma_f32_16x16x32_bf16(bl, fh, accB, 0, 0, 0);
            accB = __builtin_amdgcn_mfma_f32_16x16x32_bf16(bm, fm, accB, 0, 0, 0);
        }

        const int orow = m0 + wi * 16 + q * 4;
        const int ocol = n0 + wj * 16 + l15;
        #pragma unroll
        for (int r = 0; r < 4; r++) {
            pbf[(size_t)(orow + r) * 256 + ocol] = __float2bfloat16(fmaxf(accA[r], 0.f));
            mbf[(size_t)(orow + r) * 256 + ocol] = __float2bfloat16(accB[r] <= 0.f ? 1.f : 0.f);
        }
    }

    grid_barrier(bar + 2, bar + 3, gridDim.x);

    // ---------------- phase 2: out = p @ msk^T, 64x64 per block ----------------
    {
        const int i0 = (blockIdx.x >> 4) * 64;
        const int j0 = (blockIdx.x & 15) * 64;
        const int w  = tid >> 6;
        const int lane = tid & 63;
        const int l15 = lane & 15;
        const int q   = lane >> 4;

        const int arow = i0 + w * 16 + l15;     // wave w covers rows i0+16w..+15
        const short* ps = (const short*)pbf + (size_t)arow * 256;
        const short* ms = (const short*)mbf;

        f32x4 acc[4];
        #pragma unroll
        for (int c = 0; c < 4; c++) acc[c] = (f32x4){0.f, 0.f, 0.f, 0.f};

        #pragma unroll
        for (int k0 = 0; k0 < 256; k0 += 32) {
            const int ko = k0 + q * 8;
            bf16x8 av = *(const bf16x8*)(ps + ko);
            #pragma unroll
            for (int c = 0; c < 4; c++) {
                bf16x8 bv = *(const bf16x8*)(ms + (size_t)(j0 + c * 16 + l15) * 256 + ko);
                acc[c] = __builtin_amdgcn_mfma_f32_16x16x32_bf16(av, bv, acc[c], 0, 0, 0);
            }
        }

        const int orow = i0 + w * 16 + q * 4;
        const int ocol = j0 + l15;
        #pragma unroll
        for (int c = 0; c < 4; c++)
            #pragma unroll
            for (int r = 0; r < 4; r++)
                out[(size_t)(orow + r) * 1024 + ocol + c * 16] = acc[c][r];
    }
}

extern "C" void kernel_launch(void* const* d_in, const int* in_sizes, int n_in,
                              void* d_out, int out_size, void* d_ws, size_t ws_size,
                              hipStream_t stream) {
    const float* a     = (const float*)d_in[0];   // 1024x512
    const float* b     = (const float*)d_in[1];   // 1024x512
    const float* feats = (const float*)d_in[2];   // 256x512
    float* out = (float*)d_out;                   // 1024x1024

    char* base = (char*)d_ws;
    unsigned* bar = (unsigned*)base;              // 4 cells, zeroed below
    const size_t MB = 1024 * 1024;
    __hip_bfloat16* Ah  = (__hip_bfloat16*)(base + 1024);
    __hip_bfloat16* Am  = (__hip_bfloat16*)(base + 1024 + 1 * MB);
    __hip_bfloat16* Bh  = (__hip_bfloat16*)(base + 1024 + 2 * MB);
    __hip_bfloat16* Bm  = (__hip_bfloat16*)(base + 1024 + 3 * MB);
    __hip_bfloat16* Bl  = (__hip_bfloat16*)(base + 1024 + 4 * MB);
    __hip_bfloat16* Fh  = (__hip_bfloat16*)(base + 1024 + 5 * MB);
    __hip_bfloat16* Fm  = (__hip_bfloat16*)(base + 1024 + 5 * MB + 256 * 1024);
    __hip_bfloat16* Fl  = (__hip_bfloat16*)(base + 1024 + 5 * MB + 512 * 1024);
    __hip_bfloat16* pbf = (__hip_bfloat16*)(base + 1024 + 6 * MB);
    __hip_bfloat16* mbf = (__hip_bfloat16*)(base + 1024 + 6 * MB + 512 * 1024);

    hipMemsetAsync(bar, 0, 64, stream);           // reset barrier cells (ws is poisoned)
    fused_kernel<<<256, 256, 0, stream>>>(a, b, feats, bar,
                                          Ah, Am, Bh, Bm, Bl, Fh, Fm, Fl,
                                          pbf, mbf, out);
}

// Round 5
// 91.783 us; speedup vs baseline: 1.4247x; 1.4247x over previous
//
#include <hip/hip_runtime.h>
#include <hip/hip_bf16.h>

// out[i,j] = sum_k relu(a@feats^T)[i,k] * ((b@feats^T)[j,k] <= 0)
// Na=Nb=1024, D=512, K=256.
//
// SINGLE launch, ONE grid barrier (round 4 had two, and its RMW-spin barrier
// congested a single cache line with device-scope atomicAdd RMWs -> ~60us stall;
// this round polls with relaxed atomic LOADS + s_sleep backoff).
//
// phase 1: stage1 MFMA with IN-REGISTER f32->bf16 split conversion (no convert
//          pass, no split planes, no first barrier). Per k-iter each lane loads
//          8 f32 of a, b, feats rows; splits a->(h,m), b,f->(h,m,l); 9 MFMAs:
//          A-job accA += ah*fh + ah*fm + am*fh          (relu path, ~3e-4 err ok)
//          B-job accB += bh*fh+bh*fm+bm*fh+bh*fl+bl*fh+bm*fm  (sign f32-equivalent)
// [grid barrier: release fence -> relaxed arrival add -> relaxed load-poll -> acquire fence]
// phase 2: out(1024x1024) = p @ msk^T, 64x64 tile/block, MFMA bf16 (verified).

typedef short bf16x8 __attribute__((ext_vector_type(8)));
typedef float f32x4  __attribute__((ext_vector_type(4)));

__device__ inline void split2s(float x, short& h, short& m) {
    __hip_bfloat16 hb = __float2bfloat16(x);
    float r1 = x - __bfloat162float(hb);
    __hip_bfloat16 mb = __float2bfloat16(r1);
    h = *(short*)&hb; m = *(short*)&mb;
}

__device__ inline void split3s(float x, short& h, short& m, short& l) {
    __hip_bfloat16 hb = __float2bfloat16(x);
    float r1 = x - __bfloat162float(hb);
    __hip_bfloat16 mb = __float2bfloat16(r1);
    float r2 = r1 - __bfloat162float(mb);
    __hip_bfloat16 lb = __float2bfloat16(r2);
    h = *(short*)&hb; m = *(short*)&mb; l = *(short*)&lb;
}

__device__ inline void grid_barrier(unsigned* cnt, unsigned* flag, int nblk) {
    __syncthreads();
    if (threadIdx.x == 0) {
        __threadfence();   // release: drain this block's global writes
        unsigned prev = __hip_atomic_fetch_add(cnt, 1u, __ATOMIC_RELAXED,
                                               __HIP_MEMORY_SCOPE_AGENT);
        if (prev == (unsigned)(nblk - 1)) {
            __hip_atomic_store(flag, 1u, __ATOMIC_RELAXED, __HIP_MEMORY_SCOPE_AGENT);
        } else {
            // Poll with LOADS (no line exclusivity) + ~0.85us sleep backoff.
            while (__hip_atomic_load(flag, __ATOMIC_RELAXED,
                                     __HIP_MEMORY_SCOPE_AGENT) == 0u)
                __builtin_amdgcn_s_sleep(32);
        }
        __threadfence();   // acquire: invalidate stale cached lines
    }
    __syncthreads();
}

__global__ __launch_bounds__(256) void fused_kernel(
    const float* __restrict__ a, const float* __restrict__ b, const float* __restrict__ f,
    unsigned* __restrict__ bar,
    __hip_bfloat16* __restrict__ pbf, __hip_bfloat16* __restrict__ mbf,
    float* __restrict__ out)
{
    const int tid  = threadIdx.x;
    const int w    = tid >> 6;
    const int lane = tid & 63;
    const int l15  = lane & 15;
    const int q    = lane >> 4;

    // ---------------- phase 1: stage1 with inline conversion ----------------
    {
        const int jb = blockIdx.x;            // 0..255
        const int m0 = (jb >> 3) * 32;        // 32 row-tiles
        const int n0 = (jb & 7) * 32;         // 8 feats-tiles
        const int wi = w >> 1, wj = w & 1;

        const float* ap = a + (size_t)(m0 + wi * 16 + l15) * 512;
        const float* bp = b + (size_t)(m0 + wi * 16 + l15) * 512;
        const float* fp = f + (size_t)(n0 + wj * 16 + l15) * 512;

        f32x4 accA = {0.f, 0.f, 0.f, 0.f};
        f32x4 accB = {0.f, 0.f, 0.f, 0.f};

        #pragma unroll 2
        for (int k0 = 0; k0 < 512; k0 += 32) {
            const int ko = k0 + q * 8;
            float4 a0 = *(const float4*)(ap + ko);
            float4 a1 = *(const float4*)(ap + ko + 4);
            float4 b0 = *(const float4*)(bp + ko);
            float4 b1 = *(const float4*)(bp + ko + 4);
            float4 f0 = *(const float4*)(fp + ko);
            float4 f1 = *(const float4*)(fp + ko + 4);

            bf16x8 ah, am, bh, bm, bl, fh, fm, fl;
            const float av_[8] = {a0.x, a0.y, a0.z, a0.w, a1.x, a1.y, a1.z, a1.w};
            const float bv_[8] = {b0.x, b0.y, b0.z, b0.w, b1.x, b1.y, b1.z, b1.w};
            const float fv_[8] = {f0.x, f0.y, f0.z, f0.w, f1.x, f1.y, f1.z, f1.w};
            #pragma unroll
            for (int i = 0; i < 8; i++) {
                short h, m, l;
                split2s(av_[i], h, m);        ah[i] = h; am[i] = m;
                split3s(bv_[i], h, m, l);     bh[i] = h; bm[i] = m; bl[i] = l;
                split3s(fv_[i], h, m, l);     fh[i] = h; fm[i] = m; fl[i] = l;
            }

            accA = __builtin_amdgcn_mfma_f32_16x16x32_bf16(ah, fh, accA, 0, 0, 0);
            accB = __builtin_amdgcn_mfma_f32_16x16x32_bf16(bh, fh, accB, 0, 0, 0);
            accA = __builtin_amdgcn_mfma_f32_16x16x32_bf16(ah, fm, accA, 0, 0, 0);
            accB = __builtin_amdgcn_mfma_f32_16x16x32_bf16(bh, fm, accB, 0, 0, 0);
            accA = __builtin_amdgcn_mfma_f32_16x16x32_bf16(am, fh, accA, 0, 0, 0);
            accB = __builtin_amdgcn_mfma_f32_16x16x32_bf16(bm, fh, accB, 0, 0, 0);
            accB = __builtin_amdgcn_mfma_f32_16x16x32_bf16(bh, fl, accB, 0, 0, 0);
            accB = __builtin_amdgcn_mfma_f32_16x16x32_bf16(bl, fh, accB, 0, 0, 0);
            accB = __builtin_amdgcn_mfma_f32_16x16x32_bf16(bm, fm, accB, 0, 0, 0);
        }

        const int orow = m0 + wi * 16 + q * 4;
        const int ocol = n0 + wj * 16 + l15;
        #pragma unroll
        for (int r = 0; r < 4; r++) {
            pbf[(size_t)(orow + r) * 256 + ocol] = __float2bfloat16(fmaxf(accA[r], 0.f));
            mbf[(size_t)(orow + r) * 256 + ocol] = __float2bfloat16(accB[r] <= 0.f ? 1.f : 0.f);
        }
    }

    grid_barrier(bar + 0, bar + 16, gridDim.x);   // cells on separate cache lines

    // ---------------- phase 2: out = p @ msk^T, 64x64 per block ----------------
    {
        const int i0 = (blockIdx.x >> 4) * 64;
        const int j0 = (blockIdx.x & 15) * 64;

        const short* ps = (const short*)pbf + (size_t)(i0 + w * 16 + l15) * 256;
        const short* ms = (const short*)mbf;

        f32x4 acc[4];
        #pragma unroll
        for (int c = 0; c < 4; c++) acc[c] = (f32x4){0.f, 0.f, 0.f, 0.f};

        #pragma unroll
        for (int k0 = 0; k0 < 256; k0 += 32) {
            const int ko = k0 + q * 8;
            bf16x8 av = *(const bf16x8*)(ps + ko);
            #pragma unroll
            for (int c = 0; c < 4; c++) {
                bf16x8 bv = *(const bf16x8*)(ms + (size_t)(j0 + c * 16 + l15) * 256 + ko);
                acc[c] = __builtin_amdgcn_mfma_f32_16x16x32_bf16(av, bv, acc[c], 0, 0, 0);
            }
        }

        const int orow = i0 + w * 16 + q * 4;
        const int ocol = j0 + l15;
        #pragma unroll
        for (int c = 0; c < 4; c++)
            #pragma unroll
            for (int r = 0; r < 4; r++)
                out[(size_t)(orow + r) * 1024 + ocol + c * 16] = acc[c][r];
    }
}

extern "C" void kernel_launch(void* const* d_in, const int* in_sizes, int n_in,
                              void* d_out, int out_size, void* d_ws, size_t ws_size,
                              hipStream_t stream) {
    const float* a     = (const float*)d_in[0];   // 1024x512
    const float* b     = (const float*)d_in[1];   // 1024x512
    const float* feats = (const float*)d_in[2];   // 256x512
    float* out = (float*)d_out;                   // 1024x1024

    char* base = (char*)d_ws;
    unsigned* bar = (unsigned*)base;                                  // 128 B: cnt @0, flag @64
    __hip_bfloat16* pbf = (__hip_bfloat16*)(base + 1024);             // 1024x256 bf16
    __hip_bfloat16* mbf = pbf + 1024 * 256;

    hipMemsetAsync(bar, 0, 128, stream);          // reset barrier cells (ws poisoned 0xAA)
    fused_kernel<<<256, 256, 0, stream>>>(a, b, feats, bar, pbf, mbf, out);
}

// Round 6
// 83.317 us; speedup vs baseline: 1.5694x; 1.1016x over previous
//
#include <hip/hip_runtime.h>
#include <hip/hip_bf16.h>

// out[i,j] = sum_k relu(a@feats^T)[i,k] * ((b@feats^T)[j,k] <= 0)
// Na=Nb=1024, D=512, K=256.
//
// TWO launches, no grid barrier (R4/R5 showed single-launch + device barrier
// costs ~25us more than a plain stream dependency), no convert pass:
//
// stage1: p = relu(a@f^T) as bf16, msk = (b@f^T<=0) as bf16 {0,1}.
//   In-register TRUNCATION bf16 split (bit ops, ~5 VALU/element vs ~16 for RNE):
//     x = h + m (+ l), h = hi16(x), m = hi16(x-h), l = hi16(x-h-m).
//   A-side 2-term (3 MFMA/iter): p abs err ~1e-2 — swamped by p's own bf16 store.
//   B-side 3-term (6 MFMA/iter): sign band ~2e-5 << f32-vs-f64 ref band ~2e-3
//     that already produced the stable absmax=8.0 in the all-f32 round 1.
//   Block = 16 a-rows AND 16 b-rows x 32 cols; waves 0,1 -> p-tile, 2,3 -> msk-tile
//   (identical block durations). 512 blocks = 2/CU.
//
// gemm2 : out(1024x1024) = p @ msk^T, MFMA bf16 16x16x32 (verified frag layout:
//   A/B row=lane&15, k=(lane>>4)*8+j; C/D col=lane&15, row=(lane>>4)*4+reg).
//   32x64 tile/block, 2x2 waves of 16x32, 512 blocks = 2/CU.

typedef short bf16x8 __attribute__((ext_vector_type(8)));
typedef float f32x4  __attribute__((ext_vector_type(4)));

__device__ inline void tsplit2_8(const float* x, bf16x8& h, bf16x8& m) {
    #pragma unroll
    for (int i = 0; i < 8; i++) {
        unsigned xu = __float_as_uint(x[i]);
        unsigned hu = xu & 0xFFFF0000u;
        float r1 = x[i] - __uint_as_float(hu);
        h[i] = (short)(xu >> 16);
        m[i] = (short)(__float_as_uint(r1) >> 16);
    }
}

__device__ inline void tsplit3_8(const float* x, bf16x8& h, bf16x8& m, bf16x8& l) {
    #pragma unroll
    for (int i = 0; i < 8; i++) {
        unsigned xu = __float_as_uint(x[i]);
        unsigned hu = xu & 0xFFFF0000u;
        float r1 = x[i] - __uint_as_float(hu);
        unsigned mu = __float_as_uint(r1) & 0xFFFF0000u;
        float r2 = r1 - __uint_as_float(mu);
        h[i] = (short)(xu >> 16);
        m[i] = (short)(mu >> 16);
        l[i] = (short)(__float_as_uint(r2) >> 16);
    }
}

__global__ __launch_bounds__(256) void stage1_kernel(
    const float* __restrict__ a, const float* __restrict__ b,
    const float* __restrict__ f,
    __hip_bfloat16* __restrict__ pbf, __hip_bfloat16* __restrict__ mbf)
{
    // 512 blocks = 64 row-tiles (16 rows of a AND b each) x 8 col-tiles (32 cols)
    const int rt = blockIdx.x >> 3;          // 0..63
    const int n0 = (blockIdx.x & 7) * 32;    // 0..224
    const int tid  = threadIdx.x;
    const int w    = tid >> 6;               // 0..3
    const int lane = tid & 63;
    const int l15  = lane & 15;
    const int q    = lane >> 4;

    const int r0 = rt * 16;
    const int nw = n0 + (w & 1) * 16;        // this wave's 16 feats-cols
    const bool isA = (w < 2);

    const float* xp = (isA ? a : b) + (size_t)(r0 + l15) * 512;
    const float* fp = f + (size_t)(nw + l15) * 512;

    f32x4 acc = {0.f, 0.f, 0.f, 0.f};

    if (isA) {
        #pragma unroll 2
        for (int k0 = 0; k0 < 512; k0 += 32) {
            const int ko = k0 + q * 8;
            float xv[8], fv[8];
            *(float4*)(xv)     = *(const float4*)(xp + ko);
            *(float4*)(xv + 4) = *(const float4*)(xp + ko + 4);
            *(float4*)(fv)     = *(const float4*)(fp + ko);
            *(float4*)(fv + 4) = *(const float4*)(fp + ko + 4);
            bf16x8 xh, xm, fh, fm;
            tsplit2_8(xv, xh, xm);
            tsplit2_8(fv, fh, fm);
            acc = __builtin_amdgcn_mfma_f32_16x16x32_bf16(xh, fh, acc, 0, 0, 0);
            acc = __builtin_amdgcn_mfma_f32_16x16x32_bf16(xh, fm, acc, 0, 0, 0);
            acc = __builtin_amdgcn_mfma_f32_16x16x32_bf16(xm, fh, acc, 0, 0, 0);
        }
        #pragma unroll
        for (int r = 0; r < 4; r++)
            pbf[(size_t)(r0 + q * 4 + r) * 256 + nw + l15] =
                __float2bfloat16(fmaxf(acc[r], 0.f));
    } else {
        #pragma unroll 2
        for (int k0 = 0; k0 < 512; k0 += 32) {
            const int ko = k0 + q * 8;
            float xv[8], fv[8];
            *(float4*)(xv)     = *(const float4*)(xp + ko);
            *(float4*)(xv + 4) = *(const float4*)(xp + ko + 4);
            *(float4*)(fv)     = *(const float4*)(fp + ko);
            *(float4*)(fv + 4) = *(const float4*)(fp + ko + 4);
            bf16x8 xh, xm, xl, fh, fm, fl;
            tsplit3_8(xv, xh, xm, xl);
            tsplit3_8(fv, fh, fm, fl);
            acc = __builtin_amdgcn_mfma_f32_16x16x32_bf16(xh, fh, acc, 0, 0, 0);
            acc = __builtin_amdgcn_mfma_f32_16x16x32_bf16(xh, fm, acc, 0, 0, 0);
            acc = __builtin_amdgcn_mfma_f32_16x16x32_bf16(xm, fh, acc, 0, 0, 0);
            acc = __builtin_amdgcn_mfma_f32_16x16x32_bf16(xh, fl, acc, 0, 0, 0);
            acc = __builtin_amdgcn_mfma_f32_16x16x32_bf16(xl, fh, acc, 0, 0, 0);
            acc = __builtin_amdgcn_mfma_f32_16x16x32_bf16(xm, fm, acc, 0, 0, 0);
        }
        #pragma unroll
        for (int r = 0; r < 4; r++)
            mbf[(size_t)(r0 + q * 4 + r) * 256 + nw + l15] =
                __float2bfloat16(acc[r] <= 0.f ? 1.f : 0.f);
    }
}

__global__ __launch_bounds__(256) void gemm2_kernel(
    const __hip_bfloat16* __restrict__ p, const __hip_bfloat16* __restrict__ m,
    float* __restrict__ out)
{
    // 512 blocks = 32 i-tiles (32 rows) x 16 j-tiles (64 cols); 2x2 waves of 16x32.
    const int i0 = (blockIdx.x >> 4) * 32;
    const int j0 = (blockIdx.x & 15) * 64;
    const int tid  = threadIdx.x;
    const int w    = tid >> 6;
    const int lane = tid & 63;
    const int l15  = lane & 15;
    const int q    = lane >> 4;
    const int wi = w >> 1, wj = w & 1;

    const short* ps = (const short*)p + (size_t)(i0 + wi * 16 + l15) * 256;
    const short* ms0 = (const short*)m + (size_t)(j0 + wj * 32 + l15) * 256;
    const short* ms1 = ms0 + (size_t)16 * 256;

    f32x4 acc0 = {0.f, 0.f, 0.f, 0.f};
    f32x4 acc1 = {0.f, 0.f, 0.f, 0.f};

    #pragma unroll
    for (int k0 = 0; k0 < 256; k0 += 32) {
        const int ko = k0 + q * 8;
        bf16x8 av = *(const bf16x8*)(ps  + ko);
        bf16x8 b0 = *(const bf16x8*)(ms0 + ko);
        bf16x8 b1 = *(const bf16x8*)(ms1 + ko);
        acc0 = __builtin_amdgcn_mfma_f32_16x16x32_bf16(av, b0, acc0, 0, 0, 0);
        acc1 = __builtin_amdgcn_mfma_f32_16x16x32_bf16(av, b1, acc1, 0, 0, 0);
    }

    const int orow = i0 + wi * 16 + q * 4;
    const int ocol = j0 + wj * 32 + l15;
    #pragma unroll
    for (int r = 0; r < 4; r++) {
        out[(size_t)(orow + r) * 1024 + ocol]      = acc0[r];
        out[(size_t)(orow + r) * 1024 + ocol + 16] = acc1[r];
    }
}

extern "C" void kernel_launch(void* const* d_in, const int* in_sizes, int n_in,
                              void* d_out, int out_size, void* d_ws, size_t ws_size,
                              hipStream_t stream) {
    const float* a     = (const float*)d_in[0];   // 1024x512
    const float* b     = (const float*)d_in[1];   // 1024x512
    const float* feats = (const float*)d_in[2];   // 256x512
    float* out = (float*)d_out;                   // 1024x1024

    __hip_bfloat16* pbf = (__hip_bfloat16*)d_ws;  // 1024x256 bf16
    __hip_bfloat16* mbf = pbf + 1024 * 256;       // 1024x256 bf16

    stage1_kernel<<<512, 256, 0, stream>>>(a, b, feats, pbf, mbf);
    gemm2_kernel <<<512, 256, 0, stream>>>(pbf, mbf, out);
}